// Round 4
// baseline (322.408 us; speedup 1.0000x reference)
//
#include <hip/hip_runtime.h>

#define HH 512
#define WW 512
#define NPIX (HH*WW)      // 2^18
#define BATCH 16
#define NIMG 32           // 16 ref + 16 tgt

typedef unsigned char uchar;

// ---------------- Stage 1: luminance (float4 vectorized) ----------
__global__ __launch_bounds__(256) void k_lum(const float4* __restrict__ ref,
                                             const float4* __restrict__ tgt,
                                             float4* __restrict__ lum) {
    int idx = blockIdx.x * 256 + threadIdx.x;     // NIMG * NPIX/4 threads
    int img = idx >> 16;                          // NPIX/4 = 65536
    int p4 = idx & 65535;
    const float4* src = (img < BATCH) ? (ref + (size_t)img * 3 * 65536)
                                      : (tgt + (size_t)(img - BATCH) * 3 * 65536);
    float4 r = src[p4];
    float4 g = src[65536 + p4];
    float4 b = src[131072 + p4];
    float4 o;
    o.x = 0.299f * r.x + 0.587f * g.x + 0.114f * b.x;
    o.y = 0.299f * r.y + 0.587f * g.y + 0.114f * b.y;
    o.z = 0.299f * r.z + 0.587f * g.z + 0.114f * b.z;
    o.w = 0.299f * r.w + 0.587f * g.w + 0.114f * b.w;
    lum[idx] = o;
}

// ------ Stage 2+3 fused: sobel edge + separable 5x5 dilation -> packed M ----
// M = (1-E) | (1-Edil)<<1  (E<=Edil since dilation window includes center)
#define SS 38   // lum tile: 32 + 2*3 halo
#define ES 36   // E tile:   32 + 2*2 halo

__global__ __launch_bounds__(256) void k_sobel_dilate(const float* __restrict__ lum,
                                                      uchar* __restrict__ M) {
    __shared__ float Ls[SS * SS];
    __shared__ int Es[ES * ES];
    __shared__ int HD[ES * 32];    // horizontal 5-OR results

    int bi = blockIdx.x;
    int img = bi >> 8;             // 256 tiles per image
    int t = bi & 255;
    int y0 = (t >> 4) << 5;
    int x0 = (t & 15) << 5;
    const float* L = lum + (size_t)img * NPIX;

    for (int i = threadIdx.x; i < SS * SS; i += 256) {
        int r = i / SS, c = i - r * SS;
        int gy = y0 - 3 + r, gx = x0 - 3 + c;
        Ls[i] = ((unsigned)gy < HH && (unsigned)gx < WW) ? L[gy * WW + gx] : 0.0f;
    }
    __syncthreads();

    for (int i = threadIdx.x; i < ES * ES; i += 256) {
        int r = i / ES, c = i - r * ES;
        int gy = y0 - 2 + r, gx = x0 - 2 + c;
        int e = 0;
        if ((unsigned)gy < HH && (unsigned)gx < WW) {
            int base = (r + 1) * SS + (c + 1);
            float v00 = Ls[base - SS - 1], v01 = Ls[base - SS], v02 = Ls[base - SS + 1];
            float v10 = Ls[base - 1],                            v12 = Ls[base + 1];
            float v20 = Ls[base + SS - 1], v21 = Ls[base + SS], v22 = Ls[base + SS + 1];
            float gxv = (v02 - v00) + 2.0f * (v12 - v10) + (v22 - v20);
            float gyv = (v20 - v00) + 2.0f * (v21 - v01) + (v22 - v02);
            float grad = sqrtf(gxv * gxv + gyv * gyv + 1e-12f);
            e = (grad > 0.1f) ? 1 : 0;
        }
        Es[i] = e;
    }
    __syncthreads();

    // horizontal 5-OR: HD[r][x] = OR Es[r][x..x+4], r in [0,36), x in [0,32)
    for (int i = threadIdx.x; i < ES * 32; i += 256) {
        int r = i >> 5, x = i & 31;
        const int* row = &Es[r * ES + x];
        HD[i] = row[0] | row[1] | row[2] | row[3] | row[4];
    }
    __syncthreads();

#pragma unroll
    for (int k = 0; k < 4; ++k) {
        int j = threadIdx.x + (k << 8);
        int y = j >> 5, x = j & 31;
        int ed = HD[y * 32 + x] | HD[(y + 1) * 32 + x] | HD[(y + 2) * 32 + x]
               | HD[(y + 3) * 32 + x] | HD[(y + 4) * 32 + x];
        int e = Es[(y + 2) * ES + (x + 2)];
        M[(size_t)img * NPIX + (y0 + y) * WW + (x0 + x)] =
            (uchar)((e ^ 1) | ((ed ^ 1) << 1));
    }
}

// ---------------- Stage 4: masked 7x7 local variance (sliding separable) ----
// u = 1-E, v = 1-Edil; prox sums = u-sums - v-sums, bg sums = v-sums.
#define VS 38              // 32 + 2*3 halo

__inline__ __device__ float wave_reduce(float v) {
#pragma unroll
    for (int o = 32; o > 0; o >>= 1) v += __shfl_down(v, o);
    return v;
}

__global__ __launch_bounds__(256) void k_var(const float* __restrict__ lum,
                                             const uchar* __restrict__ M,
                                             double* __restrict__ acc) {
    __shared__ uint2 S[VS * VS];       // (lum bits, mask u|v<<1): 11552 B
    __shared__ float2 HsA[VS * 32];    // (cu, s1u)
    __shared__ float2 HsB[VS * 32];    // (s2u, cv)
    __shared__ float2 HsC[VS * 32];    // (s1v, s2v)
    __shared__ float red[4][4];

    int bi = blockIdx.x;
    int img = bi >> 8;
    int t = bi & 255;
    int y0 = (t >> 4) << 5;
    int x0 = (t & 15) << 5;
    const float* L = lum + (size_t)img * NPIX;
    const uchar* Mi = M + (size_t)img * NPIX;

    // ---- stage inputs (zero outside image) ----
    for (int i = threadIdx.x; i < VS * VS; i += 256) {
        int r = i / VS, c = i - r * VS;
        int gy = y0 - 3 + r, gx = x0 - 3 + c;
        float l = 0.0f; unsigned m = 0;
        if ((unsigned)gy < HH && (unsigned)gx < WW) {
            int q = gy * WW + gx;
            l = L[q];
            m = Mi[q];
        }
        S[i] = make_uint2(__float_as_uint(l), m);
    }
    __syncthreads();

    // ---- phase 1: horizontal sliding 7-sums, 38 rows x 8 segments of 4 ----
#define TAP_ADD(tv) { float l = __uint_as_float((tv).x); \
        float u = (float)((tv).y & 1u); float v = (float)((tv).y >> 1); \
        float ul = u * l, vl = v * l; \
        cu += u; s1u += ul; s2u = fmaf(ul, l, s2u); \
        cv += v; s1v += vl; s2v = fmaf(vl, l, s2v); }
#define TAP_SUB(tv) { float l = __uint_as_float((tv).x); \
        float u = (float)((tv).y & 1u); float v = (float)((tv).y >> 1); \
        float ul = u * l, vl = v * l; \
        cu -= u; s1u -= ul; s2u = fmaf(-ul, l, s2u); \
        cv -= v; s1v -= vl; s2v = fmaf(-vl, l, s2v); }

    for (int i = threadIdx.x; i < VS * 8; i += 256) {
        int r = i >> 3, s = i & 7;
        int cc0 = s << 2;
        const uint2* row = &S[r * VS];
        float cu = 0, s1u = 0, s2u = 0, cv = 0, s1v = 0, s2v = 0;
#pragma unroll
        for (int dx = 0; dx < 7; ++dx) { uint2 tv = row[cc0 + dx]; TAP_ADD(tv); }
        int item = r * 32 + cc0;
        HsA[item] = make_float2(cu, s1u);
        HsB[item] = make_float2(s2u, cv);
        HsC[item] = make_float2(s1v, s2v);
#pragma unroll
        for (int c = 1; c < 4; ++c) {
            uint2 ta = row[cc0 + c + 6]; TAP_ADD(ta);
            uint2 ts = row[cc0 + c - 1]; TAP_SUB(ts);
            HsA[item + c] = make_float2(cu, s1u);
            HsB[item + c] = make_float2(s2u, cv);
            HsC[item + c] = make_float2(s1v, s2v);
        }
    }
    __syncthreads();

    // ---- phase 2: vertical sliding 7-sums + variance ----
    int x = threadIdx.x & 31;
    int ybase = (threadIdx.x >> 5) << 2;   // 8 groups of 4 consecutive rows
    float cu = 0, s1u = 0, s2u = 0, cv = 0, s1v = 0, s2v = 0;
    float c0a = 0, c1a = 0, c2a = 0, c3a = 0;

#define ROW_ADD(r) { int it = (r) * 32 + x; \
        float2 pa = HsA[it], pb = HsB[it], pc = HsC[it]; \
        cu += pa.x; s1u += pa.y; s2u += pb.x; cv += pb.y; s1v += pc.x; s2v += pc.y; }
#define ROW_SUB(r) { int it = (r) * 32 + x; \
        float2 pa = HsA[it], pb = HsB[it], pc = HsC[it]; \
        cu -= pa.x; s1u -= pa.y; s2u -= pb.x; cv -= pb.y; s1v -= pc.x; s2v -= pc.y; }
#define PIXEL(yy) { \
        unsigned m0 = S[((yy) + 3) * VS + (x + 3)].y; \
        float mp0 = (m0 == 1u) ? 1.0f : 0.0f; \
        float mb0 = (float)(m0 >> 1); \
        float cp = cu - cv, s1p = s1u - s1v, s2p = s2u - s2v; \
        float Cp = fmaxf(cp, 1.0f); \
        float meanp = s1p / Cp; \
        float varp = fmaxf(s2p / Cp - meanp * meanp, 0.0f); \
        float Cb = fmaxf(cv, 1.0f); \
        float meanb = s1v / Cb; \
        float varb = fmaxf(s2v / Cb - meanb * meanb, 0.0f); \
        c0a += varp * mp0; c1a += mp0; \
        c2a += varb * mb0; c3a += mb0; }

#pragma unroll
    for (int dy = 0; dy < 7; ++dy) ROW_ADD(ybase + dy);
    PIXEL(ybase);
#pragma unroll
    for (int k = 1; k < 4; ++k) {
        ROW_ADD(ybase + k + 6);
        ROW_SUB(ybase + k - 1);
        PIXEL(ybase + k);
    }

    int lane = threadIdx.x & 63;
    int wid = threadIdx.x >> 6;
    c0a = wave_reduce(c0a); c1a = wave_reduce(c1a);
    c2a = wave_reduce(c2a); c3a = wave_reduce(c3a);
    if (lane == 0) { red[wid][0] = c0a; red[wid][1] = c1a; red[wid][2] = c2a; red[wid][3] = c3a; }
    __syncthreads();
    if (threadIdx.x == 0) {
        double t0 = 0, t1 = 0, t2 = 0, t3 = 0;
        for (int w = 0; w < 4; ++w) { t0 += red[w][0]; t1 += red[w][1]; t2 += red[w][2]; t3 += red[w][3]; }
        atomicAdd(&acc[img * 4 + 0], t0);
        atomicAdd(&acc[img * 4 + 1], t1);
        atomicAdd(&acc[img * 4 + 2], t2);
        atomicAdd(&acc[img * 4 + 3], t3);
    }
}

// ---------------- Stage 5a: per-image ringing flags ----------------
__global__ void k_flags(const double* __restrict__ acc, float* __restrict__ flags) {
    int i = threadIdx.x;
    if (i >= NIMG) return;
    const double* a = acc + (size_t)i * 4;
    double vp = a[0] / fmax(a[1], 1.0);
    double vb = a[2] / fmax(a[3], 1.0);
    flags[i] = ((vp / (vb + 1e-12)) > 2.0) ? 1.0f : 0.0f;
}

// ---------------- Stage 5b: output ----------------
__global__ __launch_bounds__(256) void k_out(const uchar4* __restrict__ M,
                                             const float* __restrict__ flags,
                                             float4* __restrict__ out) {
    int idx = blockIdx.x * 256 + threadIdx.x;   // BATCH * NPIX/4 threads
    int b = idx >> 16;
    int p = idx & 65535;
    float fr = flags[b], ft = flags[b + BATCH];
    uchar4 mr = M[(size_t)b * 65536 + p];
    uchar4 mt = M[(size_t)(b + BATCH) * 65536 + p];
    float4 o;
    o.x = fmaxf((mt.x == 1 ? ft : 0.0f) - (mr.x == 1 ? fr : 0.0f), 0.0f);
    o.y = fmaxf((mt.y == 1 ? ft : 0.0f) - (mr.y == 1 ? fr : 0.0f), 0.0f);
    o.z = fmaxf((mt.z == 1 ? ft : 0.0f) - (mr.z == 1 ? fr : 0.0f), 0.0f);
    o.w = fmaxf((mt.w == 1 ? ft : 0.0f) - (mr.w == 1 ? fr : 0.0f), 0.0f);
    out[idx] = o;
}

extern "C" void kernel_launch(void* const* d_in, const int* in_sizes, int n_in,
                              void* d_out, int out_size, void* d_ws, size_t ws_size,
                              hipStream_t stream) {
    const float* ref = (const float*)d_in[0];
    const float* tgt = (const float*)d_in[1];
    float* out = (float*)d_out;

    char* ws = (char*)d_ws;
    double* acc = (double*)ws;                       // 32*4 doubles = 1 KB
    float* flags = (float*)(ws + 1024);              // 32 floats
    float* lum = (float*)(ws + 2048);                // 32 MB
    uchar* M = (uchar*)(ws + 2048 + (size_t)NIMG * NPIX * 4);   // 8 MB

    (void)hipMemsetAsync(acc, 0, NIMG * 4 * sizeof(double), stream);

    int nAll = NIMG * NPIX;          // 8388608
    k_lum<<<nAll / 4 / 256, 256, 0, stream>>>((const float4*)ref, (const float4*)tgt, (float4*)lum);
    k_sobel_dilate<<<NIMG * 256, 256, 0, stream>>>(lum, M);
    k_var<<<NIMG * 256, 256, 0, stream>>>(lum, M, acc);
    k_flags<<<1, 64, 0, stream>>>(acc, flags);
    k_out<<<BATCH * NPIX / 4 / 256, 256, 0, stream>>>((const uchar4*)M, flags, (float4*)out);
}

// Round 5
// 311.291 us; speedup vs baseline: 1.0357x; 1.0357x over previous
//
#include <hip/hip_runtime.h>

#define HH 512
#define WW 512
#define NPIX (HH*WW)      // 2^18
#define BATCH 16
#define NIMG 32           // 16 ref + 16 tgt

typedef unsigned char uchar;

// ---------------- Stage 1: luminance (float4 vectorized) ----------
__global__ __launch_bounds__(256) void k_lum(const float4* __restrict__ ref,
                                             const float4* __restrict__ tgt,
                                             float4* __restrict__ lum) {
    int idx = blockIdx.x * 256 + threadIdx.x;     // NIMG * NPIX/4 threads
    int img = idx >> 16;                          // NPIX/4 = 65536
    int p4 = idx & 65535;
    const float4* src = (img < BATCH) ? (ref + (size_t)img * 3 * 65536)
                                      : (tgt + (size_t)(img - BATCH) * 3 * 65536);
    float4 r = src[p4];
    float4 g = src[65536 + p4];
    float4 b = src[131072 + p4];
    float4 o;
    o.x = 0.299f * r.x + 0.587f * g.x + 0.114f * b.x;
    o.y = 0.299f * r.y + 0.587f * g.y + 0.114f * b.y;
    o.z = 0.299f * r.z + 0.587f * g.z + 0.114f * b.z;
    o.w = 0.299f * r.w + 0.587f * g.w + 0.114f * b.w;
    lum[idx] = o;
}

// ------ Stage 2+3 fused: sobel edge + separable 5x5 dilation -> packed M ----
// M = p | v<<1 where p = Edil & !E (prox mask), v = !Edil (bg mask).
// (E <= Edil since the dilation window includes the center.)
#define SS 38   // lum tile: 32 + 2*3 halo
#define ES 36   // E tile:   32 + 2*2 halo

__global__ __launch_bounds__(256) void k_sobel_dilate(const float* __restrict__ lum,
                                                      uchar* __restrict__ M) {
    __shared__ float Ls[SS * SS];
    __shared__ int Es[ES * ES];
    __shared__ int HD[ES * 32];    // horizontal 5-OR results

    int bi = blockIdx.x;
    int img = bi >> 8;             // 256 tiles per image
    int t = bi & 255;
    int y0 = (t >> 4) << 5;
    int x0 = (t & 15) << 5;
    const float* L = lum + (size_t)img * NPIX;

    for (int i = threadIdx.x; i < SS * SS; i += 256) {
        int r = i / SS, c = i - r * SS;
        int gy = y0 - 3 + r, gx = x0 - 3 + c;
        Ls[i] = ((unsigned)gy < HH && (unsigned)gx < WW) ? L[gy * WW + gx] : 0.0f;
    }
    __syncthreads();

    for (int i = threadIdx.x; i < ES * ES; i += 256) {
        int r = i / ES, c = i - r * ES;
        int gy = y0 - 2 + r, gx = x0 - 2 + c;
        int e = 0;
        if ((unsigned)gy < HH && (unsigned)gx < WW) {
            int base = (r + 1) * SS + (c + 1);
            float v00 = Ls[base - SS - 1], v01 = Ls[base - SS], v02 = Ls[base - SS + 1];
            float v10 = Ls[base - 1],                            v12 = Ls[base + 1];
            float v20 = Ls[base + SS - 1], v21 = Ls[base + SS], v22 = Ls[base + SS + 1];
            float gxv = (v02 - v00) + 2.0f * (v12 - v10) + (v22 - v20);
            float gyv = (v20 - v00) + 2.0f * (v21 - v01) + (v22 - v02);
            float grad = sqrtf(gxv * gxv + gyv * gyv + 1e-12f);
            e = (grad > 0.1f) ? 1 : 0;
        }
        Es[i] = e;
    }
    __syncthreads();

    // horizontal 5-OR: HD[r][x] = OR Es[r][x..x+4], r in [0,36), x in [0,32)
    for (int i = threadIdx.x; i < ES * 32; i += 256) {
        int r = i >> 5, x = i & 31;
        const int* row = &Es[r * ES + x];
        HD[i] = row[0] | row[1] | row[2] | row[3] | row[4];
    }
    __syncthreads();

#pragma unroll
    for (int k = 0; k < 4; ++k) {
        int j = threadIdx.x + (k << 8);
        int y = j >> 5, x = j & 31;
        int ed = HD[y * 32 + x] | HD[(y + 1) * 32 + x] | HD[(y + 2) * 32 + x]
               | HD[(y + 3) * 32 + x] | HD[(y + 4) * 32 + x];
        int e = Es[(y + 2) * ES + (x + 2)];
        int p = ed & (e ^ 1);
        int v = ed ^ 1;
        M[(size_t)img * NPIX + (y0 + y) * WW + (x0 + x)] = (uchar)(p | (v << 1));
    }
}

// ---------------- Stage 4: masked 7x7 local variance (sliding separable) ----
// p = prox mask, v = bg mask; accumulate 3 moments per mask.
// All LDS row strides odd => every access <=2 lanes/bank (free on CDNA4).
#define VS 38              // 32 + 2*3 halo
#define LSTR 39            // (l, m) staging stride
#define HSTR 33            // horizontal-sum plane stride

__inline__ __device__ float wave_reduce(float v) {
#pragma unroll
    for (int o = 32; o > 0; o >>= 1) v += __shfl_down(v, o);
    return v;
}

__global__ __launch_bounds__(256) void k_var(const float* __restrict__ lum,
                                             const uchar* __restrict__ M,
                                             double* __restrict__ acc) {
    __shared__ float Lf[VS * LSTR];        // 5928 B
    __shared__ unsigned Mu[VS * LSTR];     // 5928 B
    __shared__ float Pc [VS * HSTR];       // 5016 B each x6
    __shared__ float Ps1[VS * HSTR];
    __shared__ float Ps2[VS * HSTR];
    __shared__ float Vc [VS * HSTR];
    __shared__ float Vs1[VS * HSTR];
    __shared__ float Vs2[VS * HSTR];
    __shared__ float red[4][4];

    int bi = blockIdx.x;
    int img = bi >> 8;
    int t = bi & 255;
    int y0 = (t >> 4) << 5;
    int x0 = (t & 15) << 5;
    const float* L = lum + (size_t)img * NPIX;
    const uchar* Mi = M + (size_t)img * NPIX;

    // ---- stage inputs (zero outside image) ----
    for (int i = threadIdx.x; i < VS * VS; i += 256) {
        int r = i / VS, c = i - r * VS;
        int gy = y0 - 3 + r, gx = x0 - 3 + c;
        float l = 0.0f; unsigned m = 0;
        if ((unsigned)gy < HH && (unsigned)gx < WW) {
            int q = gy * WW + gx;
            l = L[q];
            m = Mi[q];
        }
        Lf[r * LSTR + c] = l;
        Mu[r * LSTR + c] = m;
    }
    __syncthreads();

    // ---- phase 1: horizontal sliding 7-sums: 38 rows x 8 segments of 4 ----
#define TAP_ADD(j) { float l = Lf[base + (j)]; unsigned m = Mu[base + (j)]; \
        float p = (float)(m & 1u); float v = (float)(m >> 1); \
        float pl = p * l, vl = v * l; \
        cp += p; s1p += pl; s2p = fmaf(pl, l, s2p); \
        cv += v; s1v += vl; s2v = fmaf(vl, l, s2v); }
#define TAP_SUB(j) { float l = Lf[base + (j)]; unsigned m = Mu[base + (j)]; \
        float p = (float)(m & 1u); float v = (float)(m >> 1); \
        float pl = p * l, vl = v * l; \
        cp -= p; s1p -= pl; s2p = fmaf(-pl, l, s2p); \
        cv -= v; s1v -= vl; s2v = fmaf(-vl, l, s2v); }
#define HS_STORE(c) { int it = itm + (c); \
        Pc[it] = cp; Ps1[it] = s1p; Ps2[it] = s2p; \
        Vc[it] = cv; Vs1[it] = s1v; Vs2[it] = s2v; }

    for (int i = threadIdx.x; i < VS * 8; i += 256) {
        int r = i >> 3, s = i & 7;
        int cc0 = s << 2;
        int base = r * LSTR + cc0;
        int itm = r * HSTR + cc0;
        float cp = 0, s1p = 0, s2p = 0, cv = 0, s1v = 0, s2v = 0;
#pragma unroll
        for (int dx = 0; dx < 7; ++dx) TAP_ADD(dx);
        HS_STORE(0);
#pragma unroll
        for (int c = 1; c < 4; ++c) {
            TAP_ADD(c + 6);
            TAP_SUB(c - 1);
            HS_STORE(c);
        }
    }
    __syncthreads();

    // ---- phase 2: vertical sliding 7-sums + variance ----
    int x = threadIdx.x & 31;
    int ybase = (threadIdx.x >> 5) << 2;   // 8 groups of 4 consecutive rows
    float cp = 0, s1p = 0, s2p = 0, cv = 0, s1v = 0, s2v = 0;
    float c0a = 0, c1a = 0, c2a = 0, c3a = 0;

#define ROW_ADD(r) { int it = (r) * HSTR + x; \
        cp += Pc[it]; s1p += Ps1[it]; s2p += Ps2[it]; \
        cv += Vc[it]; s1v += Vs1[it]; s2v += Vs2[it]; }
#define ROW_SUB(r) { int it = (r) * HSTR + x; \
        cp -= Pc[it]; s1p -= Ps1[it]; s2p -= Ps2[it]; \
        cv -= Vc[it]; s1v -= Vs1[it]; s2v -= Vs2[it]; }
#define PIXEL(yy) { \
        unsigned m0 = Mu[((yy) + 3) * LSTR + (x + 3)]; \
        float mp0 = (float)(m0 & 1u); \
        float mb0 = (float)(m0 >> 1); \
        float Cp = fmaxf(cp, 1.0f); \
        float meanp = s1p / Cp; \
        float varp = fmaxf(s2p / Cp - meanp * meanp, 0.0f); \
        float Cb = fmaxf(cv, 1.0f); \
        float meanb = s1v / Cb; \
        float varb = fmaxf(s2v / Cb - meanb * meanb, 0.0f); \
        c0a += varp * mp0; c1a += mp0; \
        c2a += varb * mb0; c3a += mb0; }

#pragma unroll
    for (int dy = 0; dy < 7; ++dy) ROW_ADD(ybase + dy);
    PIXEL(ybase);
#pragma unroll
    for (int k = 1; k < 4; ++k) {
        ROW_ADD(ybase + k + 6);
        ROW_SUB(ybase + k - 1);
        PIXEL(ybase + k);
    }

    int lane = threadIdx.x & 63;
    int wid = threadIdx.x >> 6;
    c0a = wave_reduce(c0a); c1a = wave_reduce(c1a);
    c2a = wave_reduce(c2a); c3a = wave_reduce(c3a);
    if (lane == 0) { red[wid][0] = c0a; red[wid][1] = c1a; red[wid][2] = c2a; red[wid][3] = c3a; }
    __syncthreads();
    if (threadIdx.x == 0) {
        double t0 = 0, t1 = 0, t2 = 0, t3 = 0;
        for (int w = 0; w < 4; ++w) { t0 += red[w][0]; t1 += red[w][1]; t2 += red[w][2]; t3 += red[w][3]; }
        atomicAdd(&acc[img * 4 + 0], t0);
        atomicAdd(&acc[img * 4 + 1], t1);
        atomicAdd(&acc[img * 4 + 2], t2);
        atomicAdd(&acc[img * 4 + 3], t3);
    }
}

// ---------------- Stage 5a: per-image ringing flags ----------------
__global__ void k_flags(const double* __restrict__ acc, float* __restrict__ flags) {
    int i = threadIdx.x;
    if (i >= NIMG) return;
    const double* a = acc + (size_t)i * 4;
    double vp = a[0] / fmax(a[1], 1.0);
    double vb = a[2] / fmax(a[3], 1.0);
    flags[i] = ((vp / (vb + 1e-12)) > 2.0) ? 1.0f : 0.0f;
}

// ---------------- Stage 5b: output ----------------
__global__ __launch_bounds__(256) void k_out(const uchar4* __restrict__ M,
                                             const float* __restrict__ flags,
                                             float4* __restrict__ out) {
    int idx = blockIdx.x * 256 + threadIdx.x;   // BATCH * NPIX/4 threads
    int b = idx >> 16;
    int p = idx & 65535;
    float fr = flags[b], ft = flags[b + BATCH];
    uchar4 mr = M[(size_t)b * 65536 + p];
    uchar4 mt = M[(size_t)(b + BATCH) * 65536 + p];
    float4 o;
    o.x = fmaxf(((mt.x & 1) ? ft : 0.0f) - ((mr.x & 1) ? fr : 0.0f), 0.0f);
    o.y = fmaxf(((mt.y & 1) ? ft : 0.0f) - ((mr.y & 1) ? fr : 0.0f), 0.0f);
    o.z = fmaxf(((mt.z & 1) ? ft : 0.0f) - ((mr.z & 1) ? fr : 0.0f), 0.0f);
    o.w = fmaxf(((mt.w & 1) ? ft : 0.0f) - ((mr.w & 1) ? fr : 0.0f), 0.0f);
    out[idx] = o;
}

extern "C" void kernel_launch(void* const* d_in, const int* in_sizes, int n_in,
                              void* d_out, int out_size, void* d_ws, size_t ws_size,
                              hipStream_t stream) {
    const float* ref = (const float*)d_in[0];
    const float* tgt = (const float*)d_in[1];
    float* out = (float*)d_out;

    char* ws = (char*)d_ws;
    double* acc = (double*)ws;                       // 32*4 doubles = 1 KB
    float* flags = (float*)(ws + 1024);              // 32 floats
    float* lum = (float*)(ws + 2048);                // 32 MB
    uchar* M = (uchar*)(ws + 2048 + (size_t)NIMG * NPIX * 4);   // 8 MB

    (void)hipMemsetAsync(acc, 0, NIMG * 4 * sizeof(double), stream);

    int nAll = NIMG * NPIX;          // 8388608
    k_lum<<<nAll / 4 / 256, 256, 0, stream>>>((const float4*)ref, (const float4*)tgt, (float4*)lum);
    k_sobel_dilate<<<NIMG * 256, 256, 0, stream>>>(lum, M);
    k_var<<<NIMG * 256, 256, 0, stream>>>(lum, M, acc);
    k_flags<<<1, 64, 0, stream>>>(acc, flags);
    k_out<<<BATCH * NPIX / 4 / 256, 256, 0, stream>>>((const uchar4*)M, flags, (float4*)out);
}

// Round 6
// 276.522 us; speedup vs baseline: 1.1659x; 1.1257x over previous
//
#include <hip/hip_runtime.h>

#define HH 512
#define WW 512
#define NPIX (HH*WW)      // 2^18
#define BATCH 16
#define NIMG 32           // 16 ref + 16 tgt

typedef unsigned char uchar;

// ---------------- Stage 1: luminance (float4 vectorized) ----------
__global__ __launch_bounds__(256) void k_lum(const float4* __restrict__ ref,
                                             const float4* __restrict__ tgt,
                                             float4* __restrict__ lum) {
    int idx = blockIdx.x * 256 + threadIdx.x;     // NIMG * NPIX/4 threads
    int img = idx >> 16;                          // NPIX/4 = 65536
    int p4 = idx & 65535;
    const float4* src = (img < BATCH) ? (ref + (size_t)img * 3 * 65536)
                                      : (tgt + (size_t)(img - BATCH) * 3 * 65536);
    float4 r = src[p4];
    float4 g = src[65536 + p4];
    float4 b = src[131072 + p4];
    float4 o;
    o.x = 0.299f * r.x + 0.587f * g.x + 0.114f * b.x;
    o.y = 0.299f * r.y + 0.587f * g.y + 0.114f * b.y;
    o.z = 0.299f * r.z + 0.587f * g.z + 0.114f * b.z;
    o.w = 0.299f * r.w + 0.587f * g.w + 0.114f * b.w;
    lum[idx] = o;
}

// ------ Stage 2+3 fused: sobel edge + separable 5x5 dilation -> packed M ----
// M = p | v<<1 where p = Edil & !E (prox mask), v = !Edil (bg mask).
#define SS 38   // lum tile: 32 + 2*3 halo
#define ES 36   // E tile:   32 + 2*2 halo

__global__ __launch_bounds__(256) void k_sobel_dilate(const float* __restrict__ lum,
                                                      uchar* __restrict__ M) {
    __shared__ float Ls[SS * SS];
    __shared__ int Es[ES * ES];
    __shared__ int HD[ES * 32];    // horizontal 5-OR results

    int bi = blockIdx.x;
    int img = bi >> 8;             // 256 tiles per image
    int t = bi & 255;
    int y0 = (t >> 4) << 5;
    int x0 = (t & 15) << 5;
    const float* L = lum + (size_t)img * NPIX;

    for (int i = threadIdx.x; i < SS * SS; i += 256) {
        int r = i / SS, c = i - r * SS;
        int gy = y0 - 3 + r, gx = x0 - 3 + c;
        Ls[i] = ((unsigned)gy < HH && (unsigned)gx < WW) ? L[gy * WW + gx] : 0.0f;
    }
    __syncthreads();

    for (int i = threadIdx.x; i < ES * ES; i += 256) {
        int r = i / ES, c = i - r * ES;
        int gy = y0 - 2 + r, gx = x0 - 2 + c;
        int e = 0;
        if ((unsigned)gy < HH && (unsigned)gx < WW) {
            int base = (r + 1) * SS + (c + 1);
            float v00 = Ls[base - SS - 1], v01 = Ls[base - SS], v02 = Ls[base - SS + 1];
            float v10 = Ls[base - 1],                            v12 = Ls[base + 1];
            float v20 = Ls[base + SS - 1], v21 = Ls[base + SS], v22 = Ls[base + SS + 1];
            float gxv = (v02 - v00) + 2.0f * (v12 - v10) + (v22 - v20);
            float gyv = (v20 - v00) + 2.0f * (v21 - v01) + (v22 - v02);
            float grad = sqrtf(gxv * gxv + gyv * gyv + 1e-12f);
            e = (grad > 0.1f) ? 1 : 0;
        }
        Es[i] = e;
    }
    __syncthreads();

    for (int i = threadIdx.x; i < ES * 32; i += 256) {
        int r = i >> 5, x = i & 31;
        const int* row = &Es[r * ES + x];
        HD[i] = row[0] | row[1] | row[2] | row[3] | row[4];
    }
    __syncthreads();

#pragma unroll
    for (int k = 0; k < 4; ++k) {
        int j = threadIdx.x + (k << 8);
        int y = j >> 5, x = j & 31;
        int ed = HD[y * 32 + x] | HD[(y + 1) * 32 + x] | HD[(y + 2) * 32 + x]
               | HD[(y + 3) * 32 + x] | HD[(y + 4) * 32 + x];
        int e = Es[(y + 2) * ES + (x + 2)];
        int p = ed & (e ^ 1);
        int v = ed ^ 1;
        M[(size_t)img * NPIX + (y0 + y) * WW + (x0 + x)] = (uchar)(p | (v << 1));
    }
}

// ---------------- Stage 4: masked 7x7 local variance (sliding separable) ----
// Phase 1 reads (lum, M) directly from global (L1-hot); horizontal sliding
// 7-sums stored as 3 float2 LDS planes (odd stride 33). Phase 2 slides
// vertically. LDS ~30 KB -> 5 blocks/CU.
#define VS 38              // 32 + 2*3 halo
#define HSTR 33            // H-plane stride in float2 units (odd)

__inline__ __device__ float wave_reduce(float v) {
#pragma unroll
    for (int o = 32; o > 0; o >>= 1) v += __shfl_down(v, o);
    return v;
}

__global__ __launch_bounds__(256) void k_var(const float* __restrict__ lum,
                                             const uchar* __restrict__ M,
                                             double* __restrict__ acc) {
    __shared__ float2 PA[VS * HSTR];   // (cp, s1p)   10032 B
    __shared__ float2 PB[VS * HSTR];   // (s2p, cv)
    __shared__ float2 PC[VS * HSTR];   // (s1v, s2v)
    __shared__ float red[4][4];

    int bi = blockIdx.x;
    int img = bi >> 8;
    int t = bi & 255;
    int y0 = (t >> 4) << 5;
    int x0 = (t & 15) << 5;
    const float* L = lum + (size_t)img * NPIX;
    const uchar* Mi = M + (size_t)img * NPIX;

    bool interior = (y0 >= 32) && (y0 <= HH - 64) && (x0 >= 32) && (x0 <= WW - 64);

#define TAPV(l_, m_, sgn) { float p = (float)((m_) & 1u); float v = (float)((m_) >> 1); \
        float pl = p * (l_), vl = v * (l_); \
        cp sgn##= p; s1p sgn##= pl; s2p = fmaf(sgn pl, (l_), s2p); \
        cv sgn##= v; s1v sgn##= vl; s2v = fmaf(sgn vl, (l_), s2v); }
#define HS_STORE(c) { int it = itm + (c); \
        PA[it] = make_float2(cp, s1p); \
        PB[it] = make_float2(s2p, cv); \
        PC[it] = make_float2(s1v, s2v); }

    // ---- phase 1: horizontal sliding 7-sums: 38 rows x 8 segments of 4 ----
    if (interior) {
        for (int i = threadIdx.x; i < VS * 8; i += 256) {
            int r = i >> 3, s = i & 7;
            int cc0 = s << 2;
            const float* lrow = L + (y0 - 3 + r) * WW + (x0 - 3 + cc0);
            const uchar* mrow = Mi + (y0 - 3 + r) * WW + (x0 - 3 + cc0);
            int itm = r * HSTR + cc0;
            float cp = 0, s1p = 0, s2p = 0, cv = 0, s1v = 0, s2v = 0;
#pragma unroll
            for (int dx = 0; dx < 7; ++dx) { float l = lrow[dx]; unsigned m = mrow[dx]; TAPV(l, m, +); }
            HS_STORE(0);
#pragma unroll
            for (int c = 1; c < 4; ++c) {
                { float l = lrow[c + 6]; unsigned m = mrow[c + 6]; TAPV(l, m, +); }
                { float l = lrow[c - 1]; unsigned m = mrow[c - 1]; TAPV(l, m, -); }
                HS_STORE(c);
            }
        }
    } else {
        for (int i = threadIdx.x; i < VS * 8; i += 256) {
            int r = i >> 3, s = i & 7;
            int cc0 = s << 2;
            int gy = y0 - 3 + r;
            bool rowok = (unsigned)gy < HH;
            const float* lrow = L + gy * WW + (x0 - 3 + cc0);
            const uchar* mrow = Mi + gy * WW + (x0 - 3 + cc0);
            int itm = r * HSTR + cc0;
            float cp = 0, s1p = 0, s2p = 0, cv = 0, s1v = 0, s2v = 0;
#pragma unroll
            for (int dx = 0; dx < 7; ++dx) {
                int gx = x0 - 3 + cc0 + dx;
                bool ok = rowok && ((unsigned)gx < WW);
                float l = ok ? lrow[dx] : 0.0f;
                unsigned m = ok ? (unsigned)mrow[dx] : 0u;
                TAPV(l, m, +);
            }
            HS_STORE(0);
#pragma unroll
            for (int c = 1; c < 4; ++c) {
                {
                    int gx = x0 - 3 + cc0 + c + 6;
                    bool ok = rowok && ((unsigned)gx < WW);
                    float l = ok ? lrow[c + 6] : 0.0f;
                    unsigned m = ok ? (unsigned)mrow[c + 6] : 0u;
                    TAPV(l, m, +);
                }
                {
                    int gx = x0 - 3 + cc0 + c - 1;
                    bool ok = rowok && ((unsigned)gx < WW);
                    float l = ok ? lrow[c - 1] : 0.0f;
                    unsigned m = ok ? (unsigned)mrow[c - 1] : 0u;
                    TAPV(l, m, -);
                }
                HS_STORE(c);
            }
        }
    }
    __syncthreads();

    // ---- phase 2: vertical sliding 7-sums + variance ----
    int x = threadIdx.x & 31;
    int ybase = (threadIdx.x >> 5) << 2;   // 8 groups of 4 consecutive rows
    float cp = 0, s1p = 0, s2p = 0, cv = 0, s1v = 0, s2v = 0;
    float c0a = 0, c1a = 0, c2a = 0, c3a = 0;

#define ROW_ADD(r) { int it = (r) * HSTR + x; \
        float2 pa = PA[it], pb = PB[it], pc = PC[it]; \
        cp += pa.x; s1p += pa.y; s2p += pb.x; cv += pb.y; s1v += pc.x; s2v += pc.y; }
#define ROW_SUB(r) { int it = (r) * HSTR + x; \
        float2 pa = PA[it], pb = PB[it], pc = PC[it]; \
        cp -= pa.x; s1p -= pa.y; s2p -= pb.x; cv -= pb.y; s1v -= pc.x; s2v -= pc.y; }
#define PIXEL(yy) { \
        unsigned m0 = Mi[(y0 + (yy)) * WW + (x0 + x)]; \
        float mp0 = (float)(m0 & 1u); \
        float mb0 = (float)(m0 >> 1); \
        float Cp = fmaxf(cp, 1.0f); \
        float meanp = s1p / Cp; \
        float varp = fmaxf(s2p / Cp - meanp * meanp, 0.0f); \
        float Cb = fmaxf(cv, 1.0f); \
        float meanb = s1v / Cb; \
        float varb = fmaxf(s2v / Cb - meanb * meanb, 0.0f); \
        c0a += varp * mp0; c1a += mp0; \
        c2a += varb * mb0; c3a += mb0; }

#pragma unroll
    for (int dy = 0; dy < 7; ++dy) ROW_ADD(ybase + dy);
    PIXEL(ybase);
#pragma unroll
    for (int k = 1; k < 4; ++k) {
        ROW_ADD(ybase + k + 6);
        ROW_SUB(ybase + k - 1);
        PIXEL(ybase + k);
    }

    int lane = threadIdx.x & 63;
    int wid = threadIdx.x >> 6;
    c0a = wave_reduce(c0a); c1a = wave_reduce(c1a);
    c2a = wave_reduce(c2a); c3a = wave_reduce(c3a);
    if (lane == 0) { red[wid][0] = c0a; red[wid][1] = c1a; red[wid][2] = c2a; red[wid][3] = c3a; }
    __syncthreads();
    if (threadIdx.x == 0) {
        double t0 = 0, t1 = 0, t2 = 0, t3 = 0;
        for (int w = 0; w < 4; ++w) { t0 += red[w][0]; t1 += red[w][1]; t2 += red[w][2]; t3 += red[w][3]; }
        atomicAdd(&acc[img * 4 + 0], t0);
        atomicAdd(&acc[img * 4 + 1], t1);
        atomicAdd(&acc[img * 4 + 2], t2);
        atomicAdd(&acc[img * 4 + 3], t3);
    }
}

// ---------------- Stage 5a: per-image ringing flags ----------------
__global__ void k_flags(const double* __restrict__ acc, float* __restrict__ flags) {
    int i = threadIdx.x;
    if (i >= NIMG) return;
    const double* a = acc + (size_t)i * 4;
    double vp = a[0] / fmax(a[1], 1.0);
    double vb = a[2] / fmax(a[3], 1.0);
    flags[i] = ((vp / (vb + 1e-12)) > 2.0) ? 1.0f : 0.0f;
}

// ---------------- Stage 5b: output ----------------
__global__ __launch_bounds__(256) void k_out(const uchar4* __restrict__ M,
                                             const float* __restrict__ flags,
                                             float4* __restrict__ out) {
    int idx = blockIdx.x * 256 + threadIdx.x;   // BATCH * NPIX/4 threads
    int b = idx >> 16;
    int p = idx & 65535;
    float fr = flags[b], ft = flags[b + BATCH];
    uchar4 mr = M[(size_t)b * 65536 + p];
    uchar4 mt = M[(size_t)(b + BATCH) * 65536 + p];
    float4 o;
    o.x = fmaxf(((mt.x & 1) ? ft : 0.0f) - ((mr.x & 1) ? fr : 0.0f), 0.0f);
    o.y = fmaxf(((mt.y & 1) ? ft : 0.0f) - ((mr.y & 1) ? fr : 0.0f), 0.0f);
    o.z = fmaxf(((mt.z & 1) ? ft : 0.0f) - ((mr.z & 1) ? fr : 0.0f), 0.0f);
    o.w = fmaxf(((mt.w & 1) ? ft : 0.0f) - ((mr.w & 1) ? fr : 0.0f), 0.0f);
    out[idx] = o;
}

extern "C" void kernel_launch(void* const* d_in, const int* in_sizes, int n_in,
                              void* d_out, int out_size, void* d_ws, size_t ws_size,
                              hipStream_t stream) {
    const float* ref = (const float*)d_in[0];
    const float* tgt = (const float*)d_in[1];
    float* out = (float*)d_out;

    char* ws = (char*)d_ws;
    double* acc = (double*)ws;                       // 32*4 doubles = 1 KB
    float* flags = (float*)(ws + 1024);              // 32 floats
    float* lum = (float*)(ws + 2048);                // 32 MB
    uchar* M = (uchar*)(ws + 2048 + (size_t)NIMG * NPIX * 4);   // 8 MB

    (void)hipMemsetAsync(acc, 0, NIMG * 4 * sizeof(double), stream);

    int nAll = NIMG * NPIX;          // 8388608
    k_lum<<<nAll / 4 / 256, 256, 0, stream>>>((const float4*)ref, (const float4*)tgt, (float4*)lum);
    k_sobel_dilate<<<NIMG * 256, 256, 0, stream>>>(lum, M);
    k_var<<<NIMG * 256, 256, 0, stream>>>(lum, M, acc);
    k_flags<<<1, 64, 0, stream>>>(acc, flags);
    k_out<<<BATCH * NPIX / 4 / 256, 256, 0, stream>>>((const uchar4*)M, flags, (float4*)out);
}

// Round 7
// 272.590 us; speedup vs baseline: 1.1828x; 1.0144x over previous
//
#include <hip/hip_runtime.h>

#define HH 512
#define WW 512
#define NPIX (HH*WW)      // 2^18
#define BATCH 16
#define NIMG 32           // 16 ref + 16 tgt

typedef unsigned char uchar;

// ---------------- Stage 1: luminance (float4 vectorized) ----------
__global__ __launch_bounds__(256) void k_lum(const float4* __restrict__ ref,
                                             const float4* __restrict__ tgt,
                                             float4* __restrict__ lum) {
    int idx = blockIdx.x * 256 + threadIdx.x;     // NIMG * NPIX/4 threads
    int img = idx >> 16;                          // NPIX/4 = 65536
    int p4 = idx & 65535;
    const float4* src = (img < BATCH) ? (ref + (size_t)img * 3 * 65536)
                                      : (tgt + (size_t)(img - BATCH) * 3 * 65536);
    float4 r = src[p4];
    float4 g = src[65536 + p4];
    float4 b = src[131072 + p4];
    float4 o;
    o.x = 0.299f * r.x + 0.587f * g.x + 0.114f * b.x;
    o.y = 0.299f * r.y + 0.587f * g.y + 0.114f * b.y;
    o.z = 0.299f * r.z + 0.587f * g.z + 0.114f * b.z;
    o.w = 0.299f * r.w + 0.587f * g.w + 0.114f * b.w;
    lum[idx] = o;
}

// ------ Stage 2+3 fused: sobel edge + separable 5x5 dilation -> packed M ----
// M = p | v<<1 where p = Edil & !E (prox mask), v = !Edil (bg mask).
#define SS 38   // lum tile: 32 + 2*3 halo
#define ES 36   // E tile:   32 + 2*2 halo

__global__ __launch_bounds__(256) void k_sobel_dilate(const float* __restrict__ lum,
                                                      uchar* __restrict__ M) {
    __shared__ float Ls[SS * SS];
    __shared__ int Es[ES * ES];
    __shared__ int HD[ES * 32];    // horizontal 5-OR results

    int bi = blockIdx.x;
    int img = bi >> 8;             // 256 tiles per image
    int t = bi & 255;
    int y0 = (t >> 4) << 5;
    int x0 = (t & 15) << 5;
    const float* L = lum + (size_t)img * NPIX;

    for (int i = threadIdx.x; i < SS * SS; i += 256) {
        int r = i / SS, c = i - r * SS;
        int gy = y0 - 3 + r, gx = x0 - 3 + c;
        Ls[i] = ((unsigned)gy < HH && (unsigned)gx < WW) ? L[gy * WW + gx] : 0.0f;
    }
    __syncthreads();

    for (int i = threadIdx.x; i < ES * ES; i += 256) {
        int r = i / ES, c = i - r * ES;
        int gy = y0 - 2 + r, gx = x0 - 2 + c;
        int e = 0;
        if ((unsigned)gy < HH && (unsigned)gx < WW) {
            int base = (r + 1) * SS + (c + 1);
            float v00 = Ls[base - SS - 1], v01 = Ls[base - SS], v02 = Ls[base - SS + 1];
            float v10 = Ls[base - 1],                            v12 = Ls[base + 1];
            float v20 = Ls[base + SS - 1], v21 = Ls[base + SS], v22 = Ls[base + SS + 1];
            float gxv = (v02 - v00) + 2.0f * (v12 - v10) + (v22 - v20);
            float gyv = (v20 - v00) + 2.0f * (v21 - v01) + (v22 - v02);
            float grad = sqrtf(gxv * gxv + gyv * gyv + 1e-12f);
            e = (grad > 0.1f) ? 1 : 0;
        }
        Es[i] = e;
    }
    __syncthreads();

    for (int i = threadIdx.x; i < ES * 32; i += 256) {
        int r = i >> 5, x = i & 31;
        const int* row = &Es[r * ES + x];
        HD[i] = row[0] | row[1] | row[2] | row[3] | row[4];
    }
    __syncthreads();

#pragma unroll
    for (int k = 0; k < 4; ++k) {
        int j = threadIdx.x + (k << 8);
        int y = j >> 5, x = j & 31;
        int ed = HD[y * 32 + x] | HD[(y + 1) * 32 + x] | HD[(y + 2) * 32 + x]
               | HD[(y + 3) * 32 + x] | HD[(y + 4) * 32 + x];
        int e = Es[(y + 2) * ES + (x + 2)];
        int p = ed & (e ^ 1);
        int v = ed ^ 1;
        M[(size_t)img * NPIX + (y0 + y) * WW + (x0 + x)] = (uchar)(p | (v << 1));
    }
}

// ---------------- Stage 4: masked 7x7 local variance (sliding separable) ----
// Phase 1: global reads, 10 taps batched into registers, horizontal sliding
// 7-sums -> 5 scalar LDS planes (word stride 33 = odd => conflict-free):
//   Pcnt = cp | cv<<8 (ints, rolling max 56 < 256), Ps1, Ps2, Vs1, Vs2.
// Phase 2: vertical sliding 7-sums + variance. LDS 25.1 KB -> 6 blocks/CU.
#define VS 38              // 32 + 2*3 halo
#define HSTR 33            // plane stride in 4B words (odd)

__inline__ __device__ float wave_reduce(float v) {
#pragma unroll
    for (int o = 32; o > 0; o >>= 1) v += __shfl_down(v, o);
    return v;
}

__global__ __launch_bounds__(256, 6) void k_var(const float* __restrict__ lum,
                                                const uchar* __restrict__ M,
                                                double* __restrict__ acc) {
    __shared__ unsigned Pcnt[VS * HSTR];   // 5016 B each x5 = 25080 B
    __shared__ float Ps1[VS * HSTR];
    __shared__ float Ps2[VS * HSTR];
    __shared__ float Vs1[VS * HSTR];
    __shared__ float Vs2[VS * HSTR];
    __shared__ float red[4][4];

    int bi = blockIdx.x;
    int img = bi >> 8;
    int t = bi & 255;
    int y0 = (t >> 4) << 5;
    int x0 = (t & 15) << 5;
    const float* L = lum + (size_t)img * NPIX;
    const uchar* Mi = M + (size_t)img * NPIX;

    bool interior = (y0 >= 32) && (y0 <= HH - 64) && (x0 >= 32) && (x0 <= WW - 64);

    // ---- phase 1: horizontal sliding 7-sums: 38 rows x 8 segments of 4 ----
    // 256 threads cover 304 items: thread i does item i (+256 if i < 48).
    for (int i = threadIdx.x; i < VS * 8; i += 256) {
        int r = i >> 3, s = i & 7;
        int cc0 = s << 2;
        int gy = y0 - 3 + r;
        int gx0 = x0 - 3 + cc0;
        float lv[10];
        unsigned mv[10];
        if (interior) {
            const float* lrow = L + gy * WW + gx0;
            const uchar* mrow = Mi + gy * WW + gx0;
#pragma unroll
            for (int dx = 0; dx < 10; ++dx) { lv[dx] = lrow[dx]; mv[dx] = mrow[dx]; }
        } else {
            bool rowok = (unsigned)gy < HH;
            const float* lrow = L + gy * WW + gx0;
            const uchar* mrow = Mi + gy * WW + gx0;
#pragma unroll
            for (int dx = 0; dx < 10; ++dx) {
                bool ok = rowok && ((unsigned)(gx0 + dx) < WW);
                lv[dx] = ok ? lrow[dx] : 0.0f;
                mv[dx] = ok ? (unsigned)mrow[dx] : 0u;
            }
        }
        int cp = 0, cv = 0;
        float s1p = 0, s2p = 0, s1v = 0, s2v = 0;
#pragma unroll
        for (int dx = 0; dx < 7; ++dx) {
            float l = lv[dx]; unsigned m = mv[dx];
            int p = m & 1, v = m >> 1;
            float pf = (float)p, vf = (float)v;
            float pl = pf * l, vl = vf * l;
            cp += p; cv += v;
            s1p += pl; s2p = fmaf(pl, l, s2p);
            s1v += vl; s2v = fmaf(vl, l, s2v);
        }
        int itm = r * HSTR + cc0;
        Pcnt[itm] = (unsigned)cp | ((unsigned)cv << 8);
        Ps1[itm] = s1p; Ps2[itm] = s2p; Vs1[itm] = s1v; Vs2[itm] = s2v;
#pragma unroll
        for (int c = 1; c < 4; ++c) {
            {   // add tap c+6
                float l = lv[c + 6]; unsigned m = mv[c + 6];
                int p = m & 1, v = m >> 1;
                float pf = (float)p, vf = (float)v;
                float pl = pf * l, vl = vf * l;
                cp += p; cv += v;
                s1p += pl; s2p = fmaf(pl, l, s2p);
                s1v += vl; s2v = fmaf(vl, l, s2v);
            }
            {   // sub tap c-1
                float l = lv[c - 1]; unsigned m = mv[c - 1];
                int p = m & 1, v = m >> 1;
                float pf = (float)p, vf = (float)v;
                float pl = pf * l, vl = vf * l;
                cp -= p; cv -= v;
                s1p -= pl; s2p = fmaf(-pl, l, s2p);
                s1v -= vl; s2v = fmaf(-vl, l, s2v);
            }
            Pcnt[itm + c] = (unsigned)cp | ((unsigned)cv << 8);
            Ps1[itm + c] = s1p; Ps2[itm + c] = s2p; Vs1[itm + c] = s1v; Vs2[itm + c] = s2v;
        }
    }
    __syncthreads();

    // ---- phase 2: vertical sliding 7-sums + variance ----
    int x = threadIdx.x & 31;
    int ybase = (threadIdx.x >> 5) << 2;   // 8 groups of 4 consecutive rows
    unsigned mreg[4];
#pragma unroll
    for (int k = 0; k < 4; ++k)
        mreg[k] = Mi[(y0 + ybase + k) * WW + (x0 + x)];

    unsigned pc = 0;
    float s1p = 0, s2p = 0, s1v = 0, s2v = 0;
    float c0a = 0, c1a = 0, c2a = 0, c3a = 0;

#pragma unroll
    for (int dy = 0; dy < 7; ++dy) {
        int it = (ybase + dy) * HSTR + x;
        pc += Pcnt[it]; s1p += Ps1[it]; s2p += Ps2[it]; s1v += Vs1[it]; s2v += Vs2[it];
    }
#pragma unroll
    for (int k = 0; k < 4; ++k) {
        if (k > 0) {
            int ita = (ybase + k + 6) * HSTR + x;
            int its = (ybase + k - 1) * HSTR + x;
            pc += Pcnt[ita] - Pcnt[its];
            s1p += Ps1[ita] - Ps1[its];
            s2p += Ps2[ita] - Ps2[its];
            s1v += Vs1[ita] - Vs1[its];
            s2v += Vs2[ita] - Vs2[its];
        }
        unsigned m0 = mreg[k];
        float mp0 = (float)(m0 & 1u);
        float mb0 = (float)(m0 >> 1);
        float cpf = (float)(pc & 0xffu);
        float cvf = (float)(pc >> 8);
        float Cp = fmaxf(cpf, 1.0f);
        float meanp = s1p / Cp;
        float varp = fmaxf(s2p / Cp - meanp * meanp, 0.0f);
        float Cb = fmaxf(cvf, 1.0f);
        float meanb = s1v / Cb;
        float varb = fmaxf(s2v / Cb - meanb * meanb, 0.0f);
        c0a += varp * mp0; c1a += mp0;
        c2a += varb * mb0; c3a += mb0;
    }

    int lane = threadIdx.x & 63;
    int wid = threadIdx.x >> 6;
    c0a = wave_reduce(c0a); c1a = wave_reduce(c1a);
    c2a = wave_reduce(c2a); c3a = wave_reduce(c3a);
    if (lane == 0) { red[wid][0] = c0a; red[wid][1] = c1a; red[wid][2] = c2a; red[wid][3] = c3a; }
    __syncthreads();
    if (threadIdx.x == 0) {
        double t0 = 0, t1 = 0, t2 = 0, t3 = 0;
        for (int w = 0; w < 4; ++w) { t0 += red[w][0]; t1 += red[w][1]; t2 += red[w][2]; t3 += red[w][3]; }
        atomicAdd(&acc[img * 4 + 0], t0);
        atomicAdd(&acc[img * 4 + 1], t1);
        atomicAdd(&acc[img * 4 + 2], t2);
        atomicAdd(&acc[img * 4 + 3], t3);
    }
}

// ---------------- Stage 5a: per-image ringing flags ----------------
__global__ void k_flags(const double* __restrict__ acc, float* __restrict__ flags) {
    int i = threadIdx.x;
    if (i >= NIMG) return;
    const double* a = acc + (size_t)i * 4;
    double vp = a[0] / fmax(a[1], 1.0);
    double vb = a[2] / fmax(a[3], 1.0);
    flags[i] = ((vp / (vb + 1e-12)) > 2.0) ? 1.0f : 0.0f;
}

// ---------------- Stage 5b: output ----------------
__global__ __launch_bounds__(256) void k_out(const uchar4* __restrict__ M,
                                             const float* __restrict__ flags,
                                             float4* __restrict__ out) {
    int idx = blockIdx.x * 256 + threadIdx.x;   // BATCH * NPIX/4 threads
    int b = idx >> 16;
    int p = idx & 65535;
    float fr = flags[b], ft = flags[b + BATCH];
    uchar4 mr = M[(size_t)b * 65536 + p];
    uchar4 mt = M[(size_t)(b + BATCH) * 65536 + p];
    float4 o;
    o.x = fmaxf(((mt.x & 1) ? ft : 0.0f) - ((mr.x & 1) ? fr : 0.0f), 0.0f);
    o.y = fmaxf(((mt.y & 1) ? ft : 0.0f) - ((mr.y & 1) ? fr : 0.0f), 0.0f);
    o.z = fmaxf(((mt.z & 1) ? ft : 0.0f) - ((mr.z & 1) ? fr : 0.0f), 0.0f);
    o.w = fmaxf(((mt.w & 1) ? ft : 0.0f) - ((mr.w & 1) ? fr : 0.0f), 0.0f);
    out[idx] = o;
}

extern "C" void kernel_launch(void* const* d_in, const int* in_sizes, int n_in,
                              void* d_out, int out_size, void* d_ws, size_t ws_size,
                              hipStream_t stream) {
    const float* ref = (const float*)d_in[0];
    const float* tgt = (const float*)d_in[1];
    float* out = (float*)d_out;

    char* ws = (char*)d_ws;
    double* acc = (double*)ws;                       // 32*4 doubles = 1 KB
    float* flags = (float*)(ws + 1024);              // 32 floats
    float* lum = (float*)(ws + 2048);                // 32 MB
    uchar* M = (uchar*)(ws + 2048 + (size_t)NIMG * NPIX * 4);   // 8 MB

    (void)hipMemsetAsync(acc, 0, NIMG * 4 * sizeof(double), stream);

    int nAll = NIMG * NPIX;          // 8388608
    k_lum<<<nAll / 4 / 256, 256, 0, stream>>>((const float4*)ref, (const float4*)tgt, (float4*)lum);
    k_sobel_dilate<<<NIMG * 256, 256, 0, stream>>>(lum, M);
    k_var<<<NIMG * 256, 256, 0, stream>>>(lum, M, acc);
    k_flags<<<1, 64, 0, stream>>>(acc, flags);
    k_out<<<BATCH * NPIX / 4 / 256, 256, 0, stream>>>((const uchar4*)M, flags, (float4*)out);
}